// Round 5
// baseline (202.983 us; speedup 1.0000x reference)
//
#include <hip/hip_runtime.h>

#define N_FIN 128
#define N_HID 16
#define N_OUT 12
#define H2S   16          // hs2 row stride (padded to one 64B line)
#define NBLK  1024        // blocks for hist/binwrite (region layout depends on it)
#define BN    512         // nodes per bucket (dl = dst & 511, bucket = dst >> 9)

// ---------- per-(block,bucket) histogram of dst>>9 ----------
__global__ __launch_bounds__(256) void k_hist(const int* __restrict__ dst,
                                              unsigned* __restrict__ hist,
                                              int E, int chunk, int NB) {
  __shared__ unsigned lh[512];
  int t = threadIdx.x, blk = blockIdx.x;
  for (int b = t; b < NB; b += 256) lh[b] = 0u;
  __syncthreads();
  int lo = blk * chunk, hi = min(E, lo + chunk);
  for (int j = lo + t; j < hi; j += 256) atomicAdd(&lh[dst[j] >> 9], 1u);
  __syncthreads();
  for (int b = t; b < NB; b += 256) hist[(size_t)b * NBLK + blk] = lh[b];
}

// ---------- exclusive scan of hist (bucket-major) ----------
__global__ __launch_bounds__(256) void k_scan1(const unsigned* __restrict__ in,
                                               unsigned* __restrict__ out,
                                               unsigned* __restrict__ bsum, int M) {
  __shared__ unsigned s[256];
  int t = threadIdx.x, i = blockIdx.x * 256 + t;
  unsigned v = (i < M) ? in[i] : 0u;
  s[t] = v;
  __syncthreads();
#pragma unroll
  for (int off = 1; off < 256; off <<= 1) {
    unsigned y = (t >= off) ? s[t - off] : 0u;
    __syncthreads();
    s[t] += y;
    __syncthreads();
  }
  if (i < M) out[i] = s[t] - v;
  if (t == 255) bsum[blockIdx.x] = s[255];
}

__global__ __launch_bounds__(1024) void k_scan2(unsigned* __restrict__ bsum, int nb) {
  __shared__ unsigned s[1024];
  int t = threadIdx.x;
  unsigned v = (t < nb) ? bsum[t] : 0u;
  s[t] = v;
  __syncthreads();
#pragma unroll
  for (int off = 1; off < 1024; off <<= 1) {
    unsigned y = (t >= off) ? s[t - off] : 0u;
    __syncthreads();
    s[t] += y;
    __syncthreads();
  }
  if (t < nb) bsum[t] = s[t] - v;
}

__global__ __launch_bounds__(256) void k_scan3(unsigned* __restrict__ out,
                                               const unsigned* __restrict__ bsum, int M) {
  int i = blockIdx.x * 256 + threadIdx.x;
  if (i < M) out[i] += bsum[blockIdx.x];
}

// ---------- bin edges into bucket-major regions ----------
__global__ __launch_bounds__(256) void k_binwrite(const int* __restrict__ src,
                                                  const int* __restrict__ dst,
                                                  const unsigned* __restrict__ base,
                                                  unsigned* __restrict__ entries,
                                                  int E, int chunk, int NB) {
  __shared__ unsigned cur[512];
  int t = threadIdx.x, blk = blockIdx.x;
  for (int b = t; b < NB; b += 256) cur[b] = base[(size_t)b * NBLK + blk];
  __syncthreads();
  int lo = blk * chunk, hi = min(E, lo + chunk);
  for (int j = lo + t; j < hi; j += 256) {
    int d = dst[j];
    int b = d >> 9;
    unsigned pos = atomicAdd(&cur[b], 1u);
    entries[pos] = ((unsigned)src[j] << 9) | (unsigned)(d & (BN - 1));
  }
}

// ---------- per-bucket: histogram dl -> deg/dinv/row_start, then CSR order ----------
__global__ __launch_bounds__(1024) void k_bucket_csr(const unsigned* __restrict__ entries,
                                                     const unsigned* __restrict__ base,
                                                     unsigned* __restrict__ row_start,
                                                     unsigned* __restrict__ deg,
                                                     float* __restrict__ dinv,
                                                     unsigned* __restrict__ esrc,
                                                     int N, int NB, int E) {
  __shared__ unsigned cnt[BN];
  __shared__ unsigned cur[BN];
  int t = threadIdx.x, b = blockIdx.x;
  if (t < BN) cnt[t] = 0u;
  __syncthreads();
  unsigned start = base[(size_t)b * NBLK];
  unsigned end = (b + 1 < NB) ? base[(size_t)(b + 1) * NBLK] : (unsigned)E;
  for (unsigned j = start + t; j < end; j += 1024) atomicAdd(&cnt[entries[j] & (BN - 1)], 1u);
  __syncthreads();
  unsigned v = (t < BN) ? cnt[t] : 0u;
  if (t < BN) cur[t] = v;
  __syncthreads();
#pragma unroll
  for (int off = 1; off < BN; off <<= 1) {
    unsigned y = (t < BN && t >= off) ? cur[t - off] : 0u;
    __syncthreads();
    if (t < BN) cur[t] += y;
    __syncthreads();
  }
  if (t < BN) {
    unsigned excl = cur[t] - v;
    cur[t] = excl;
    int node = b * BN + t;
    if (node < N) {
      row_start[node] = start + excl;
      deg[node] = v;
      dinv[node] = rsqrtf((float)(v + 1u));
    }
  }
  __syncthreads();
  for (unsigned j = start + t; j < end; j += 1024) {
    unsigned en = entries[j];
    unsigned dl = en & (BN - 1);
    unsigned p = atomicAdd(&cur[dl], 1u);
    esrc[start + p] = en >> 9;
  }
}

// ---------------- hs = dinv * (x @ W1), x:[N,128] W1:[128,16] ----------------
__global__ __launch_bounds__(256) void k_gemm1(const float* __restrict__ x,
                                               const float* __restrict__ W1,
                                               const float* __restrict__ dinv,
                                               float* __restrict__ hs, int N) {
  __shared__ float xs[16][132];
  __shared__ float wT[16][132];
  int t = threadIdx.x;
#pragma unroll
  for (int i = 0; i < 8; ++i) {
    int idx = t + i * 256;
    int k = idx >> 4, c = idx & 15;
    wT[c][k] = W1[idx];
  }
  int row0 = blockIdx.x * 16;
#pragma unroll
  for (int i = 0; i < 2; ++i) {
    int idx = t + i * 256;
    int r = idx >> 5, c4 = idx & 31;
    float4 v = make_float4(0.f, 0.f, 0.f, 0.f);
    if (row0 + r < N) v = *(const float4*)(x + (size_t)(row0 + r) * N_FIN + c4 * 4);
    *(float4*)&xs[r][c4 * 4] = v;
  }
  __syncthreads();
  int col = t & 15, r = t >> 4;
  float acc = 0.f;
#pragma unroll
  for (int kc = 0; kc < 32; ++kc) {
    float4 xv = *(const float4*)&xs[r][kc * 4];
    float4 wv = *(const float4*)&wT[col][kc * 4];
    acc += xv.x * wv.x + xv.y * wv.y + xv.z * wv.z + xv.w * wv.w;
  }
  int row = row0 + r;
  if (row < N) hs[(size_t)row * N_HID + col] = dinv[row] * acc;
}

// ------ layer1: CSR gather + self-loop + bias + relu + 16x12 GEMM -------------
__global__ __launch_bounds__(256) void k_gagg1(const unsigned* __restrict__ esrc,
                                               const unsigned* __restrict__ row_start,
                                               const unsigned* __restrict__ deg,
                                               const float* __restrict__ hs,
                                               const float* __restrict__ dinv,
                                               const float* __restrict__ b1,
                                               const float* __restrict__ W2,
                                               float* __restrict__ hs2, int N) {
  __shared__ float os[16][N_HID + 1];
  __shared__ float w2s[N_HID][N_OUT];
  __shared__ float b1s[N_HID];
  int t = threadIdx.x;
  if (t < N_HID * N_OUT) w2s[t / N_OUT][t % N_OUT] = W2[t];
  if (t < N_HID) b1s[t] = b1[t];
  __syncthreads();
  int nl = t >> 4, c = t & 15;
  int node = blockIdx.x * 16 + nl;
  float o = 0.f;
  if (node < N) {
    unsigned s0 = row_start[node], dn = deg[node];
    float a0 = 0.f, a1 = 0.f, a2 = 0.f, a3 = 0.f;
    int gb = t & 48;  // wave-lane base of this 16-lane group
    for (unsigned j0 = 0; j0 < dn; j0 += 16) {
      unsigned idx = j0 + (unsigned)c;
      unsigned ev = (idx < dn) ? esrc[s0 + idx] : 0u;
      unsigned rem = dn - j0;
      if (rem >= 16) {
#pragma unroll
        for (int k = 0; k < 16; ++k) {
          unsigned e = (unsigned)__shfl((int)ev, gb | k, 64);
          float* a = (k & 2) ? ((k & 1) ? &a3 : &a2) : ((k & 1) ? &a1 : &a0);
          *a += hs[(size_t)e * N_HID + c];
        }
      } else {
        for (unsigned k = 0; k < rem; ++k) {
          unsigned e = (unsigned)__shfl((int)ev, gb | (int)k, 64);
          a0 += hs[(size_t)e * N_HID + c];
        }
      }
    }
    float acc = (a0 + a1) + (a2 + a3);
    o = fmaxf(dinv[node] * (acc + hs[(size_t)node * N_HID + c]) + b1s[c], 0.f);
  }
  os[nl][c] = o;
  __syncthreads();
  if (t < 16 * N_OUT) {
    int n2 = t / N_OUT, c2 = t % N_OUT;
    int node2 = blockIdx.x * 16 + n2;
    if (node2 < N) {
      float s = 0.f;
#pragma unroll
      for (int cc = 0; cc < N_HID; ++cc) s += os[n2][cc] * w2s[cc][c2];
      hs2[(size_t)node2 * H2S + c2] = dinv[node2] * s;
    }
  }
}

// ------ layer2: CSR gather + self-loop + bias + log_softmax -------------------
__global__ __launch_bounds__(256) void k_gagg2(const unsigned* __restrict__ esrc,
                                               const unsigned* __restrict__ row_start,
                                               const unsigned* __restrict__ deg,
                                               const float* __restrict__ hs2,
                                               const float* __restrict__ dinv,
                                               const float* __restrict__ b2,
                                               float* __restrict__ out, int N) {
  __shared__ float zs[16][13];
  __shared__ float ls[16];
  __shared__ float b2s[N_OUT];
  int t = threadIdx.x;
  if (t < N_OUT) b2s[t] = b2[t];
  __syncthreads();
  int nl = t >> 4, c = t & 15;
  int node = blockIdx.x * 16 + nl;
  if (node < N) {
    unsigned s0 = row_start[node], dn = deg[node];
    float a0 = 0.f, a1 = 0.f, a2 = 0.f, a3 = 0.f;
    int gb = t & 48;
    for (unsigned j0 = 0; j0 < dn; j0 += 16) {
      unsigned idx = j0 + (unsigned)c;
      unsigned ev = (idx < dn) ? esrc[s0 + idx] : 0u;
      unsigned rem = dn - j0;
      if (rem >= 16) {
#pragma unroll
        for (int k = 0; k < 16; ++k) {
          unsigned e = (unsigned)__shfl((int)ev, gb | k, 64);
          float* a = (k & 2) ? ((k & 1) ? &a3 : &a2) : ((k & 1) ? &a1 : &a0);
          *a += hs2[(size_t)e * H2S + c];
        }
      } else {
        for (unsigned k = 0; k < rem; ++k) {
          unsigned e = (unsigned)__shfl((int)ev, gb | (int)k, 64);
          a0 += hs2[(size_t)e * H2S + c];
        }
      }
    }
    if (c < N_OUT) {
      float acc = (a0 + a1) + (a2 + a3);
      zs[nl][c] = dinv[node] * (acc + hs2[(size_t)node * H2S + c]) + b2s[c];
    }
  }
  __syncthreads();
  if (c == 0 && node < N) {
    float m = zs[nl][0];
#pragma unroll
    for (int jj = 1; jj < N_OUT; ++jj) m = fmaxf(m, zs[nl][jj]);
    float sum = 0.f;
#pragma unroll
    for (int jj = 0; jj < N_OUT; ++jj) sum += __expf(zs[nl][jj] - m);
    ls[nl] = m + __logf(sum);
  }
  __syncthreads();
  if (node < N && c < N_OUT) out[(size_t)node * N_OUT + c] = zs[nl][c] - ls[nl];
}

extern "C" void kernel_launch(void* const* d_in, const int* in_sizes, int n_in,
                              void* d_out, int out_size, void* d_ws, size_t ws_size,
                              hipStream_t stream) {
  const float* x  = (const float*)d_in[0];
  const int*   ei = (const int*)d_in[1];
  const float* W1 = (const float*)d_in[2];
  const float* b1 = (const float*)d_in[3];
  const float* W2 = (const float*)d_in[4];
  const float* b2 = (const float*)d_in[5];
  int N = in_sizes[0] / N_FIN;
  int E = in_sizes[1] / 2;
  const int* src = ei;
  const int* dst = ei + E;

  int NB = (N + BN - 1) / BN;            // 196 buckets of 512 nodes
  int M  = NB * NBLK;                    // hist/base table size (~200K)
  int chunk = (E + NBLK - 1) / NBLK;     // edges per binning block
  int sb = (M + 255) / 256;              // scan blocks (784 <= 1024)

  // ws: [hist M][base M][bsum 4096B][dinv N][deg N][row_start N]
  //     [big: entries E (later aliased by hs N*16 + hs2 N*16)][esrc E]
  char* ws = (char*)d_ws;
  unsigned* hist      = (unsigned*)ws;  ws += (size_t)M * 4;
  unsigned* base      = (unsigned*)ws;  ws += (size_t)M * 4;
  unsigned* bsum      = (unsigned*)ws;  ws += 4096;
  float*    dinv      = (float*)ws;     ws += (size_t)N * 4;
  unsigned* deg       = (unsigned*)ws;  ws += (size_t)N * 4;
  unsigned* row_start = (unsigned*)ws;  ws += (size_t)N * 4;
  size_t big_bytes = (size_t)E * 4;
  size_t hs_bytes  = (size_t)N * N_HID * 4 + (size_t)N * H2S * 4;
  if (hs_bytes > big_bytes) big_bytes = hs_bytes;
  unsigned* entries = (unsigned*)ws;
  float*    hs      = (float*)ws;                              // aliases entries (dead after csr)
  float*    hs2     = (float*)(ws + (size_t)N * N_HID * 4);
  ws += big_bytes;
  unsigned* esrc    = (unsigned*)ws;

  k_hist      <<<NBLK, 256, 0, stream>>>(dst, hist, E, chunk, NB);
  k_scan1     <<<sb, 256, 0, stream>>>(hist, base, bsum, M);
  k_scan2     <<<1, 1024, 0, stream>>>(bsum, sb);
  k_scan3     <<<sb, 256, 0, stream>>>(base, bsum, M);
  k_binwrite  <<<NBLK, 256, 0, stream>>>(src, dst, base, entries, E, chunk, NB);
  k_bucket_csr<<<NB, 1024, 0, stream>>>(entries, base, row_start, deg, dinv, esrc, N, NB, E);
  k_gemm1     <<<(N + 15) / 16, 256, 0, stream>>>(x, W1, dinv, hs, N);   // overwrites entries
  k_gagg1     <<<(N + 15) / 16, 256, 0, stream>>>(esrc, row_start, deg, hs, dinv, b1, W2, hs2, N);
  k_gagg2     <<<(N + 15) / 16, 256, 0, stream>>>(esrc, row_start, deg, hs2, dinv, b2, (float*)d_out, N);
}

// Round 6
// 163.970 us; speedup vs baseline: 1.2379x; 1.2379x over previous
//
#include <hip/hip_runtime.h>
#include <hip/hip_fp16.h>

#define N_FIN 128
#define N_HID 16
#define N_OUT 12
#define NBLK  1024        // blocks for hist/binwrite (region layout depends on it)
#define BN    512         // nodes per bucket (dl = dst & 511, bucket = dst >> 9)

// ---------- per-(block,bucket) histogram of dst>>9 ----------
__global__ __launch_bounds__(256) void k_hist(const int* __restrict__ dst,
                                              unsigned* __restrict__ hist,
                                              int E, int chunk, int NB) {
  __shared__ unsigned lh[512];
  int t = threadIdx.x, blk = blockIdx.x;
  for (int b = t; b < NB; b += 256) lh[b] = 0u;
  __syncthreads();
  int lo = blk * chunk, hi = min(E, lo + chunk);
  for (int j = lo + t; j < hi; j += 256) atomicAdd(&lh[dst[j] >> 9], 1u);
  __syncthreads();
  for (int b = t; b < NB; b += 256) hist[(size_t)b * NBLK + blk] = lh[b];
}

// ---------- exclusive scan of hist (bucket-major) ----------
__global__ __launch_bounds__(256) void k_scan1(const unsigned* __restrict__ in,
                                               unsigned* __restrict__ out,
                                               unsigned* __restrict__ bsum, int M) {
  __shared__ unsigned s[256];
  int t = threadIdx.x, i = blockIdx.x * 256 + t;
  unsigned v = (i < M) ? in[i] : 0u;
  s[t] = v;
  __syncthreads();
#pragma unroll
  for (int off = 1; off < 256; off <<= 1) {
    unsigned y = (t >= off) ? s[t - off] : 0u;
    __syncthreads();
    s[t] += y;
    __syncthreads();
  }
  if (i < M) out[i] = s[t] - v;
  if (t == 255) bsum[blockIdx.x] = s[255];
}

__global__ __launch_bounds__(1024) void k_scan2(unsigned* __restrict__ bsum, int nb) {
  __shared__ unsigned s[1024];
  int t = threadIdx.x;
  unsigned v = (t < nb) ? bsum[t] : 0u;
  s[t] = v;
  __syncthreads();
#pragma unroll
  for (int off = 1; off < 1024; off <<= 1) {
    unsigned y = (t >= off) ? s[t - off] : 0u;
    __syncthreads();
    s[t] += y;
    __syncthreads();
  }
  if (t < nb) bsum[t] = s[t] - v;
}

__global__ __launch_bounds__(256) void k_scan3(unsigned* __restrict__ out,
                                               const unsigned* __restrict__ bsum, int M) {
  int i = blockIdx.x * 256 + threadIdx.x;
  if (i < M) out[i] += bsum[blockIdx.x];
}

// ---------- bin edges into bucket-major regions ----------
__global__ __launch_bounds__(256) void k_binwrite(const int* __restrict__ src,
                                                  const int* __restrict__ dst,
                                                  const unsigned* __restrict__ base,
                                                  unsigned* __restrict__ entries,
                                                  int E, int chunk, int NB) {
  __shared__ unsigned cur[512];
  int t = threadIdx.x, blk = blockIdx.x;
  for (int b = t; b < NB; b += 256) cur[b] = base[(size_t)b * NBLK + blk];
  __syncthreads();
  int lo = blk * chunk, hi = min(E, lo + chunk);
  for (int j = lo + t; j < hi; j += 256) {
    int d = dst[j];
    int b = d >> 9;
    unsigned pos = atomicAdd(&cur[b], 1u);
    entries[pos] = ((unsigned)src[j] << 9) | (unsigned)(d & (BN - 1));
  }
}

// ---------- per-bucket: histogram dl -> deg/dinv/row_start, then CSR order ----------
__global__ __launch_bounds__(1024) void k_bucket_csr(const unsigned* __restrict__ entries,
                                                     const unsigned* __restrict__ base,
                                                     unsigned* __restrict__ row_start,
                                                     unsigned* __restrict__ deg,
                                                     float* __restrict__ dinv,
                                                     unsigned* __restrict__ esrc,
                                                     int N, int NB, int E) {
  __shared__ unsigned cnt[BN];
  __shared__ unsigned cur[BN];
  int t = threadIdx.x, b = blockIdx.x;
  if (t < BN) cnt[t] = 0u;
  __syncthreads();
  unsigned start = base[(size_t)b * NBLK];
  unsigned end = (b + 1 < NB) ? base[(size_t)(b + 1) * NBLK] : (unsigned)E;
  for (unsigned j = start + t; j < end; j += 1024) atomicAdd(&cnt[entries[j] & (BN - 1)], 1u);
  __syncthreads();
  unsigned v = (t < BN) ? cnt[t] : 0u;
  if (t < BN) cur[t] = v;
  __syncthreads();
#pragma unroll
  for (int off = 1; off < BN; off <<= 1) {
    unsigned y = (t < BN && t >= off) ? cur[t - off] : 0u;
    __syncthreads();
    if (t < BN) cur[t] += y;
    __syncthreads();
  }
  if (t < BN) {
    unsigned excl = cur[t] - v;
    cur[t] = excl;
    int node = b * BN + t;
    if (node < N) {
      row_start[node] = start + excl;
      deg[node] = v;
      dinv[node] = rsqrtf((float)(v + 1u));
    }
  }
  __syncthreads();
  for (unsigned j = start + t; j < end; j += 1024) {
    unsigned en = entries[j];
    unsigned dl = en & (BN - 1);
    unsigned p = atomicAdd(&cur[dl], 1u);
    esrc[start + p] = en >> 9;
  }
}

// ---------------- hs = fp16( dinv * (x @ W1) ), x:[N,128] W1:[128,16] ----------------
__global__ __launch_bounds__(256) void k_gemm1(const float* __restrict__ x,
                                               const float* __restrict__ W1,
                                               const float* __restrict__ dinv,
                                               __half* __restrict__ hs, int N) {
  __shared__ float xs[16][132];
  __shared__ float wT[16][132];
  int t = threadIdx.x;
#pragma unroll
  for (int i = 0; i < 8; ++i) {
    int idx = t + i * 256;
    int k = idx >> 4, c = idx & 15;
    wT[c][k] = W1[idx];
  }
  int row0 = blockIdx.x * 16;
#pragma unroll
  for (int i = 0; i < 2; ++i) {
    int idx = t + i * 256;
    int r = idx >> 5, c4 = idx & 31;
    float4 v = make_float4(0.f, 0.f, 0.f, 0.f);
    if (row0 + r < N) v = *(const float4*)(x + (size_t)(row0 + r) * N_FIN + c4 * 4);
    *(float4*)&xs[r][c4 * 4] = v;
  }
  __syncthreads();
  int col = t & 15, r = t >> 4;
  float acc = 0.f;
#pragma unroll
  for (int kc = 0; kc < 32; ++kc) {
    float4 xv = *(const float4*)&xs[r][kc * 4];
    float4 wv = *(const float4*)&wT[col][kc * 4];
    acc += xv.x * wv.x + xv.y * wv.y + xv.z * wv.z + xv.w * wv.w;
  }
  int row = row0 + r;
  if (row < N) hs[(size_t)row * N_HID + col] = __float2half(dinv[row] * acc);
}

// ------ layer1: CSR gather (fp16 rows) + self-loop + bias + relu + 16x12 GEMM ------
__global__ __launch_bounds__(256) void k_gagg1(const unsigned* __restrict__ esrc,
                                               const unsigned* __restrict__ row_start,
                                               const unsigned* __restrict__ deg,
                                               const __half* __restrict__ hs,
                                               const float* __restrict__ dinv,
                                               const float* __restrict__ b1,
                                               const float* __restrict__ W2,
                                               __half* __restrict__ hs2, int N) {
  __shared__ float os[16][N_HID + 1];
  __shared__ float w2s[N_HID][N_OUT];
  __shared__ float b1s[N_HID];
  int t = threadIdx.x;
  if (t < N_HID * N_OUT) w2s[t / N_OUT][t % N_OUT] = W2[t];
  if (t < N_HID) b1s[t] = b1[t];
  __syncthreads();
  int nl = t >> 4, c = t & 15;
  int node = blockIdx.x * 16 + nl;
  float o = 0.f;
  if (node < N) {
    unsigned s0 = row_start[node], dn = deg[node];
    float a0 = 0.f, a1 = 0.f, a2 = 0.f, a3 = 0.f;
    unsigned j = 0;
    for (; j + 4 <= dn; j += 4) {
      unsigned e0 = esrc[s0 + j], e1 = esrc[s0 + j + 1];
      unsigned e2 = esrc[s0 + j + 2], e3 = esrc[s0 + j + 3];
      a0 += __half2float(hs[(size_t)e0 * N_HID + c]);
      a1 += __half2float(hs[(size_t)e1 * N_HID + c]);
      a2 += __half2float(hs[(size_t)e2 * N_HID + c]);
      a3 += __half2float(hs[(size_t)e3 * N_HID + c]);
    }
    for (; j < dn; ++j) a0 += __half2float(hs[(size_t)esrc[s0 + j] * N_HID + c]);
    float acc = (a0 + a1) + (a2 + a3);
    float self = __half2float(hs[(size_t)node * N_HID + c]);
    o = fmaxf(dinv[node] * (acc + self) + b1s[c], 0.f);
  }
  os[nl][c] = o;
  __syncthreads();
  {
    int n2 = t >> 4, c2 = t & 15;
    int node2 = blockIdx.x * 16 + n2;
    if (node2 < N) {
      float s = 0.f;
      if (c2 < N_OUT) {
#pragma unroll
        for (int cc = 0; cc < N_HID; ++cc) s += os[n2][cc] * w2s[cc][c2];
        s *= dinv[node2];
      }
      hs2[(size_t)node2 * N_HID + c2] = __float2half(s);   // pad cols 12..15 = 0
    }
  }
}

// ------ layer2: CSR gather (fp16 rows) + self-loop + bias + log_softmax ------------
__global__ __launch_bounds__(256) void k_gagg2(const unsigned* __restrict__ esrc,
                                               const unsigned* __restrict__ row_start,
                                               const unsigned* __restrict__ deg,
                                               const __half* __restrict__ hs2,
                                               const float* __restrict__ dinv,
                                               const float* __restrict__ b2,
                                               float* __restrict__ out, int N) {
  __shared__ float zs[16][13];
  __shared__ float ls[16];
  __shared__ float b2s[N_OUT];
  int t = threadIdx.x;
  if (t < N_OUT) b2s[t] = b2[t];
  __syncthreads();
  int nl = t >> 4, c = t & 15;
  int node = blockIdx.x * 16 + nl;
  if (node < N) {
    unsigned s0 = row_start[node], dn = deg[node];
    float a0 = 0.f, a1 = 0.f, a2 = 0.f, a3 = 0.f;
    unsigned j = 0;
    for (; j + 4 <= dn; j += 4) {
      unsigned e0 = esrc[s0 + j], e1 = esrc[s0 + j + 1];
      unsigned e2 = esrc[s0 + j + 2], e3 = esrc[s0 + j + 3];
      a0 += __half2float(hs2[(size_t)e0 * N_HID + c]);
      a1 += __half2float(hs2[(size_t)e1 * N_HID + c]);
      a2 += __half2float(hs2[(size_t)e2 * N_HID + c]);
      a3 += __half2float(hs2[(size_t)e3 * N_HID + c]);
    }
    for (; j < dn; ++j) a0 += __half2float(hs2[(size_t)esrc[s0 + j] * N_HID + c]);
    if (c < N_OUT) {
      float acc = (a0 + a1) + (a2 + a3);
      float self = __half2float(hs2[(size_t)node * N_HID + c]);
      zs[nl][c] = dinv[node] * (acc + self) + b2s[c];
    }
  }
  __syncthreads();
  if (c == 0 && node < N) {
    float m = zs[nl][0];
#pragma unroll
    for (int jj = 1; jj < N_OUT; ++jj) m = fmaxf(m, zs[nl][jj]);
    float sum = 0.f;
#pragma unroll
    for (int jj = 0; jj < N_OUT; ++jj) sum += __expf(zs[nl][jj] - m);
    ls[nl] = m + __logf(sum);
  }
  __syncthreads();
  if (node < N && c < N_OUT) out[(size_t)node * N_OUT + c] = zs[nl][c] - ls[nl];
}

extern "C" void kernel_launch(void* const* d_in, const int* in_sizes, int n_in,
                              void* d_out, int out_size, void* d_ws, size_t ws_size,
                              hipStream_t stream) {
  const float* x  = (const float*)d_in[0];
  const int*   ei = (const int*)d_in[1];
  const float* W1 = (const float*)d_in[2];
  const float* b1 = (const float*)d_in[3];
  const float* W2 = (const float*)d_in[4];
  const float* b2 = (const float*)d_in[5];
  int N = in_sizes[0] / N_FIN;
  int E = in_sizes[1] / 2;
  const int* src = ei;
  const int* dst = ei + E;

  int NB = (N + BN - 1) / BN;            // 196 buckets of 512 nodes
  int M  = NB * NBLK;                    // hist/base table size
  int chunk = (E + NBLK - 1) / NBLK;     // edges per binning block
  int sb = (M + 255) / 256;              // scan blocks

  // ws: [hist M][base M][bsum 4096B][dinv N][deg N][row_start N]
  //     [big: entries E (later aliased by fp16 hs N*16 + hs2 N*16)][esrc E]
  char* ws = (char*)d_ws;
  unsigned* hist      = (unsigned*)ws;  ws += (size_t)M * 4;
  unsigned* base      = (unsigned*)ws;  ws += (size_t)M * 4;
  unsigned* bsum      = (unsigned*)ws;  ws += 4096;
  float*    dinv      = (float*)ws;     ws += (size_t)N * 4;
  unsigned* deg       = (unsigned*)ws;  ws += (size_t)N * 4;
  unsigned* row_start = (unsigned*)ws;  ws += (size_t)N * 4;
  size_t big_bytes = (size_t)E * 4;
  size_t hs_bytes  = (size_t)N * N_HID * 2 * 2;   // hs + hs2, fp16
  if (hs_bytes > big_bytes) big_bytes = hs_bytes;
  unsigned* entries = (unsigned*)ws;
  __half*   hs      = (__half*)ws;                             // aliases entries (dead after csr)
  __half*   hs2     = (__half*)(ws + (size_t)N * N_HID * 2);
  ws += big_bytes;
  unsigned* esrc    = (unsigned*)ws;

  k_hist      <<<NBLK, 256, 0, stream>>>(dst, hist, E, chunk, NB);
  k_scan1     <<<sb, 256, 0, stream>>>(hist, base, bsum, M);
  k_scan2     <<<1, 1024, 0, stream>>>(bsum, sb);
  k_scan3     <<<sb, 256, 0, stream>>>(base, bsum, M);
  k_binwrite  <<<NBLK, 256, 0, stream>>>(src, dst, base, entries, E, chunk, NB);
  k_bucket_csr<<<NB, 1024, 0, stream>>>(entries, base, row_start, deg, dinv, esrc, N, NB, E);
  k_gemm1     <<<(N + 15) / 16, 256, 0, stream>>>(x, W1, dinv, hs, N);   // overwrites entries
  k_gagg1     <<<(N + 15) / 16, 256, 0, stream>>>(esrc, row_start, deg, hs, dinv, b1, W2, hs2, N);
  k_gagg2     <<<(N + 15) / 16, 256, 0, stream>>>(esrc, row_start, deg, hs2, dinv, b2, (float*)d_out, N);
}

// Round 7
// 160.537 us; speedup vs baseline: 1.2644x; 1.0214x over previous
//
#include <hip/hip_runtime.h>
#include <hip/hip_fp16.h>

#define N_FIN 128
#define N_HID 16
#define N_OUT 12
#define NBLK  1024        // blocks for hist/binwrite (region layout depends on it)
#define BN    1024        // nodes per bucket (dl = dst & 1023, bucket = dst >> 10)

// ---------- per-(block,bucket) histogram of dst>>10 ----------
__global__ __launch_bounds__(256) void k_hist(const int* __restrict__ dst,
                                              unsigned* __restrict__ hist,
                                              int E, int chunk, int NB) {
  __shared__ unsigned lh[128];
  int t = threadIdx.x, blk = blockIdx.x;
  for (int b = t; b < NB; b += 256) lh[b] = 0u;
  __syncthreads();
  int lo = blk * chunk, hi = min(E, lo + chunk);
  for (int j = lo + t; j < hi; j += 256) atomicAdd(&lh[dst[j] >> 10], 1u);
  __syncthreads();
  for (int b = t; b < NB; b += 256) hist[(size_t)b * NBLK + blk] = lh[b];
}

// ---------- exclusive scan of hist (bucket-major) ----------
__global__ __launch_bounds__(256) void k_scan1(const unsigned* __restrict__ in,
                                               unsigned* __restrict__ out,
                                               unsigned* __restrict__ bsum, int M) {
  __shared__ unsigned s[256];
  int t = threadIdx.x, i = blockIdx.x * 256 + t;
  unsigned v = (i < M) ? in[i] : 0u;
  s[t] = v;
  __syncthreads();
#pragma unroll
  for (int off = 1; off < 256; off <<= 1) {
    unsigned y = (t >= off) ? s[t - off] : 0u;
    __syncthreads();
    s[t] += y;
    __syncthreads();
  }
  if (i < M) out[i] = s[t] - v;
  if (t == 255) bsum[blockIdx.x] = s[255];
}

__global__ __launch_bounds__(1024) void k_scan2(unsigned* __restrict__ bsum, int nb) {
  __shared__ unsigned s[1024];
  int t = threadIdx.x;
  unsigned v = (t < nb) ? bsum[t] : 0u;
  s[t] = v;
  __syncthreads();
#pragma unroll
  for (int off = 1; off < 1024; off <<= 1) {
    unsigned y = (t >= off) ? s[t - off] : 0u;
    __syncthreads();
    s[t] += y;
    __syncthreads();
  }
  if (t < nb) bsum[t] = s[t] - v;
}

__global__ __launch_bounds__(256) void k_scan3(unsigned* __restrict__ out,
                                               const unsigned* __restrict__ bsum, int M) {
  int i = blockIdx.x * 256 + threadIdx.x;
  if (i < M) out[i] += bsum[blockIdx.x];
}

// ---------- bin edges into bucket-major regions ----------
__global__ __launch_bounds__(256) void k_binwrite(const int* __restrict__ src,
                                                  const int* __restrict__ dst,
                                                  const unsigned* __restrict__ base,
                                                  unsigned* __restrict__ entries,
                                                  int E, int chunk, int NB) {
  __shared__ unsigned cur[128];
  int t = threadIdx.x, blk = blockIdx.x;
  for (int b = t; b < NB; b += 256) cur[b] = base[(size_t)b * NBLK + blk];
  __syncthreads();
  int lo = blk * chunk, hi = min(E, lo + chunk);
  for (int j = lo + t; j < hi; j += 256) {
    int d = dst[j];
    int b = d >> 10;
    unsigned pos = atomicAdd(&cur[b], 1u);
    entries[pos] = ((unsigned)src[j] << 10) | (unsigned)(d & (BN - 1));
  }
}

// ---------- per-bucket: histogram dl -> deg/dinv/row_start, then CSR order ----------
__global__ __launch_bounds__(1024) void k_bucket_csr(const unsigned* __restrict__ entries,
                                                     const unsigned* __restrict__ base,
                                                     unsigned* __restrict__ row_start,
                                                     unsigned* __restrict__ deg,
                                                     float* __restrict__ dinv,
                                                     unsigned* __restrict__ esrc,
                                                     int N, int NB, int E) {
  __shared__ unsigned cnt[BN];
  __shared__ unsigned cur[BN];
  int t = threadIdx.x, b = blockIdx.x;
  cnt[t] = 0u;
  __syncthreads();
  unsigned start = base[(size_t)b * NBLK];
  unsigned end = (b + 1 < NB) ? base[(size_t)(b + 1) * NBLK] : (unsigned)E;
  for (unsigned j = start + t; j < end; j += 1024) atomicAdd(&cnt[entries[j] & (BN - 1)], 1u);
  __syncthreads();
  unsigned v = cnt[t];
  cur[t] = v;
  __syncthreads();
#pragma unroll
  for (int off = 1; off < BN; off <<= 1) {
    unsigned y = (t >= off) ? cur[t - off] : 0u;
    __syncthreads();
    cur[t] += y;
    __syncthreads();
  }
  {
    unsigned excl = cur[t] - v;
    cur[t] = excl;
    int node = b * BN + t;
    if (node < N) {
      row_start[node] = start + excl;
      deg[node] = v;
      dinv[node] = rsqrtf((float)(v + 1u));
    }
  }
  __syncthreads();
  for (unsigned j = start + t; j < end; j += 1024) {
    unsigned en = entries[j];
    unsigned dl = en & (BN - 1);
    unsigned p = atomicAdd(&cur[dl], 1u);
    esrc[start + p] = en >> 10;
  }
}

// ---------------- hs = fp16( dinv * (x @ W1) ), x:[N,128] W1:[128,16] ----------------
__global__ __launch_bounds__(256) void k_gemm1(const float* __restrict__ x,
                                               const float* __restrict__ W1,
                                               const float* __restrict__ dinv,
                                               __half* __restrict__ hs, int N) {
  __shared__ float xs[16][132];
  __shared__ float wT[16][132];
  int t = threadIdx.x;
#pragma unroll
  for (int i = 0; i < 8; ++i) {
    int idx = t + i * 256;
    int k = idx >> 4, c = idx & 15;
    wT[c][k] = W1[idx];
  }
  int row0 = blockIdx.x * 16;
#pragma unroll
  for (int i = 0; i < 2; ++i) {
    int idx = t + i * 256;
    int r = idx >> 5, c4 = idx & 31;
    float4 v = make_float4(0.f, 0.f, 0.f, 0.f);
    if (row0 + r < N) v = *(const float4*)(x + (size_t)(row0 + r) * N_FIN + c4 * 4);
    *(float4*)&xs[r][c4 * 4] = v;
  }
  __syncthreads();
  int col = t & 15, r = t >> 4;
  float acc = 0.f;
#pragma unroll
  for (int kc = 0; kc < 32; ++kc) {
    float4 xv = *(const float4*)&xs[r][kc * 4];
    float4 wv = *(const float4*)&wT[col][kc * 4];
    acc += xv.x * wv.x + xv.y * wv.y + xv.z * wv.z + xv.w * wv.w;
  }
  int row = row0 + r;
  if (row < N) hs[(size_t)row * N_HID + col] = __float2half(dinv[row] * acc);
}

// ------ layer1: CSR gather (half2, 8 lanes/node) + self + bias + relu + 16x12 GEMM ------
__global__ __launch_bounds__(256) void k_gagg1(const unsigned* __restrict__ esrc,
                                               const unsigned* __restrict__ row_start,
                                               const unsigned* __restrict__ deg,
                                               const __half2* __restrict__ hs,
                                               const float* __restrict__ dinv,
                                               const float* __restrict__ b1,
                                               const float* __restrict__ W2,
                                               __half* __restrict__ hs2, int N) {
  __shared__ float os[32][17];
  __shared__ float w2s[N_HID][N_OUT];
  __shared__ float b1s[N_HID];
  int t = threadIdx.x;
  if (t < N_HID * N_OUT) w2s[t / N_OUT][t % N_OUT] = W2[t];
  if (t < N_HID) b1s[t] = b1[t];
  int nl = t >> 3, c2 = t & 7;
  int node = blockIdx.x * 32 + nl;
  if (node < N) {
    unsigned s0 = row_start[node], dn = deg[node];
    float ax0 = 0.f, ay0 = 0.f, ax1 = 0.f, ay1 = 0.f;
    float ax2 = 0.f, ay2 = 0.f, ax3 = 0.f, ay3 = 0.f;
    unsigned j = 0;
    for (; j + 4 <= dn; j += 4) {
      unsigned e0 = esrc[s0 + j],     e1 = esrc[s0 + j + 1];
      unsigned e2 = esrc[s0 + j + 2], e3 = esrc[s0 + j + 3];
      float2 v0 = __half22float2(hs[(size_t)e0 * 8 + c2]);
      float2 v1 = __half22float2(hs[(size_t)e1 * 8 + c2]);
      float2 v2 = __half22float2(hs[(size_t)e2 * 8 + c2]);
      float2 v3 = __half22float2(hs[(size_t)e3 * 8 + c2]);
      ax0 += v0.x; ay0 += v0.y; ax1 += v1.x; ay1 += v1.y;
      ax2 += v2.x; ay2 += v2.y; ax3 += v3.x; ay3 += v3.y;
    }
    for (; j < dn; ++j) {
      float2 v = __half22float2(hs[(size_t)esrc[s0 + j] * 8 + c2]);
      ax0 += v.x; ay0 += v.y;
    }
    float2 self = __half22float2(hs[(size_t)node * 8 + c2]);
    float di = dinv[node];
    float accx = (ax0 + ax1) + (ax2 + ax3) + self.x;
    float accy = (ay0 + ay1) + (ay2 + ay3) + self.y;
    os[nl][2 * c2]     = fmaxf(di * accx + b1s[2 * c2], 0.f);
    os[nl][2 * c2 + 1] = fmaxf(di * accy + b1s[2 * c2 + 1], 0.f);
  }
  __syncthreads();
  // MLP (+ zero pad cols 12..15): 32 nodes x 16 cols
  for (int idx = t; idx < 32 * 16; idx += 256) {
    int n2 = idx >> 4, cc2 = idx & 15;
    int node2 = blockIdx.x * 32 + n2;
    if (node2 < N) {
      float s = 0.f;
      if (cc2 < N_OUT) {
#pragma unroll
        for (int cc = 0; cc < N_HID; ++cc) s += os[n2][cc] * w2s[cc][cc2];
        s *= dinv[node2];
      }
      hs2[(size_t)node2 * N_HID + cc2] = __float2half(s);
    }
  }
}

// ------ layer2: CSR gather (half2, 6 active pairs) + self + bias + log_softmax ------
__global__ __launch_bounds__(256) void k_gagg2(const unsigned* __restrict__ esrc,
                                               const unsigned* __restrict__ row_start,
                                               const unsigned* __restrict__ deg,
                                               const __half2* __restrict__ hs2,
                                               const float* __restrict__ dinv,
                                               const float* __restrict__ b2,
                                               float* __restrict__ out, int N) {
  __shared__ float zs[32][13];
  __shared__ float ls[32];
  __shared__ float b2s[N_OUT];
  int t = threadIdx.x;
  if (t < N_OUT) b2s[t] = b2[t];
  __syncthreads();
  int nl = t >> 3, c2 = t & 7;
  int node = blockIdx.x * 32 + nl;
  if (node < N && c2 < 6) {
    unsigned s0 = row_start[node], dn = deg[node];
    float ax0 = 0.f, ay0 = 0.f, ax1 = 0.f, ay1 = 0.f;
    float ax2 = 0.f, ay2 = 0.f, ax3 = 0.f, ay3 = 0.f;
    unsigned j = 0;
    for (; j + 4 <= dn; j += 4) {
      unsigned e0 = esrc[s0 + j],     e1 = esrc[s0 + j + 1];
      unsigned e2 = esrc[s0 + j + 2], e3 = esrc[s0 + j + 3];
      float2 v0 = __half22float2(hs2[(size_t)e0 * 8 + c2]);
      float2 v1 = __half22float2(hs2[(size_t)e1 * 8 + c2]);
      float2 v2 = __half22float2(hs2[(size_t)e2 * 8 + c2]);
      float2 v3 = __half22float2(hs2[(size_t)e3 * 8 + c2]);
      ax0 += v0.x; ay0 += v0.y; ax1 += v1.x; ay1 += v1.y;
      ax2 += v2.x; ay2 += v2.y; ax3 += v3.x; ay3 += v3.y;
    }
    for (; j < dn; ++j) {
      float2 v = __half22float2(hs2[(size_t)esrc[s0 + j] * 8 + c2]);
      ax0 += v.x; ay0 += v.y;
    }
    float2 self = __half22float2(hs2[(size_t)node * 8 + c2]);
    float di = dinv[node];
    zs[nl][2 * c2]     = di * ((ax0 + ax1) + (ax2 + ax3) + self.x) + b2s[2 * c2];
    zs[nl][2 * c2 + 1] = di * ((ay0 + ay1) + (ay2 + ay3) + self.y) + b2s[2 * c2 + 1];
  }
  __syncthreads();
  if (c2 == 0 && node < N) {
    float m = zs[nl][0];
#pragma unroll
    for (int jj = 1; jj < N_OUT; ++jj) m = fmaxf(m, zs[nl][jj]);
    float sum = 0.f;
#pragma unroll
    for (int jj = 0; jj < N_OUT; ++jj) sum += __expf(zs[nl][jj] - m);
    ls[nl] = m + __logf(sum);
  }
  __syncthreads();
  for (int idx = t; idx < 32 * N_OUT; idx += 256) {
    int n2 = idx / N_OUT, cc = idx % N_OUT;
    int node2 = blockIdx.x * 32 + n2;
    if (node2 < N) out[(size_t)node2 * N_OUT + cc] = zs[n2][cc] - ls[n2];
  }
}

extern "C" void kernel_launch(void* const* d_in, const int* in_sizes, int n_in,
                              void* d_out, int out_size, void* d_ws, size_t ws_size,
                              hipStream_t stream) {
  const float* x  = (const float*)d_in[0];
  const int*   ei = (const int*)d_in[1];
  const float* W1 = (const float*)d_in[2];
  const float* b1 = (const float*)d_in[3];
  const float* W2 = (const float*)d_in[4];
  const float* b2 = (const float*)d_in[5];
  int N = in_sizes[0] / N_FIN;
  int E = in_sizes[1] / 2;
  const int* src = ei;
  const int* dst = ei + E;

  int NB = (N + BN - 1) / BN;            // 98 buckets of 1024 nodes
  int M  = NB * NBLK;                    // hist/base table size (~100K)
  int chunk = (E + NBLK - 1) / NBLK;     // edges per binning block
  int sb = (M + 255) / 256;              // scan blocks (392 <= 1024)

  // ws: [hist M][base M][bsum 4096B][dinv N][deg N][row_start N]
  //     [big: entries E (later aliased by fp16 hs N*16 + hs2 N*16)][esrc E]
  char* ws = (char*)d_ws;
  unsigned* hist      = (unsigned*)ws;  ws += (size_t)M * 4;
  unsigned* base      = (unsigned*)ws;  ws += (size_t)M * 4;
  unsigned* bsum      = (unsigned*)ws;  ws += 4096;
  float*    dinv      = (float*)ws;     ws += (size_t)N * 4;
  unsigned* deg       = (unsigned*)ws;  ws += (size_t)N * 4;
  unsigned* row_start = (unsigned*)ws;  ws += (size_t)N * 4;
  size_t big_bytes = (size_t)E * 4;
  size_t hs_bytes  = (size_t)N * N_HID * 2 * 2;   // hs + hs2, fp16
  if (hs_bytes > big_bytes) big_bytes = hs_bytes;
  unsigned* entries = (unsigned*)ws;
  __half*   hs      = (__half*)ws;                             // aliases entries (dead after csr)
  __half*   hs2     = (__half*)(ws + (size_t)N * N_HID * 2);
  ws += big_bytes;
  unsigned* esrc    = (unsigned*)ws;

  k_hist      <<<NBLK, 256, 0, stream>>>(dst, hist, E, chunk, NB);
  k_scan1     <<<sb, 256, 0, stream>>>(hist, base, bsum, M);
  k_scan2     <<<1, 1024, 0, stream>>>(bsum, sb);
  k_scan3     <<<sb, 256, 0, stream>>>(base, bsum, M);
  k_binwrite  <<<NBLK, 256, 0, stream>>>(src, dst, base, entries, E, chunk, NB);
  k_bucket_csr<<<NB, 1024, 0, stream>>>(entries, base, row_start, deg, dinv, esrc, N, NB, E);
  k_gemm1     <<<(N + 15) / 16, 256, 0, stream>>>(x, W1, dinv, hs, N);   // overwrites entries
  k_gagg1     <<<(N + 31) / 32, 256, 0, stream>>>(esrc, row_start, deg, (const __half2*)hs,
                                                  dinv, b1, W2, hs2, N);
  k_gagg2     <<<(N + 31) / 32, 256, 0, stream>>>(esrc, row_start, deg, (const __half2*)hs2,
                                                  dinv, b2, (float*)d_out, N);
}

// Round 8
// 157.091 us; speedup vs baseline: 1.2921x; 1.0219x over previous
//
#include <hip/hip_runtime.h>
#include <hip/hip_fp16.h>

#define N_FIN 128
#define N_HID 16
#define N_OUT 12
#define NBLK  1024        // blocks for hist/binwrite (region layout depends on it)
#define BN    1024        // nodes per bucket (dl = dst & 1023, bucket = dst >> 10)
#define QCAP  10240       // LDS sort capacity per quarter-bucket (avg 8192)

// ---------- per-(block,bucket) histogram of dst>>10 ----------
__global__ __launch_bounds__(256) void k_hist(const int* __restrict__ dst,
                                              unsigned* __restrict__ hist,
                                              int E, int chunk, int NB) {
  __shared__ unsigned lh[128];
  int t = threadIdx.x, blk = blockIdx.x;
  for (int b = t; b < NB; b += 256) lh[b] = 0u;
  __syncthreads();
  int lo = blk * chunk, hi = min(E, lo + chunk);
  for (int j = lo + t; j < hi; j += 256) atomicAdd(&lh[dst[j] >> 10], 1u);
  __syncthreads();
  for (int b = t; b < NB; b += 256) hist[(size_t)b * NBLK + blk] = lh[b];
}

// ---------- exclusive scan of hist (bucket-major) ----------
__global__ __launch_bounds__(256) void k_scan1(const unsigned* __restrict__ in,
                                               unsigned* __restrict__ out,
                                               unsigned* __restrict__ bsum, int M) {
  __shared__ unsigned s[256];
  int t = threadIdx.x, i = blockIdx.x * 256 + t;
  unsigned v = (i < M) ? in[i] : 0u;
  s[t] = v;
  __syncthreads();
#pragma unroll
  for (int off = 1; off < 256; off <<= 1) {
    unsigned y = (t >= off) ? s[t - off] : 0u;
    __syncthreads();
    s[t] += y;
    __syncthreads();
  }
  if (i < M) out[i] = s[t] - v;
  if (t == 255) bsum[blockIdx.x] = s[255];
}

__global__ __launch_bounds__(1024) void k_scan2(unsigned* __restrict__ bsum, int nb) {
  __shared__ unsigned s[1024];
  int t = threadIdx.x;
  unsigned v = (t < nb) ? bsum[t] : 0u;
  s[t] = v;
  __syncthreads();
#pragma unroll
  for (int off = 1; off < 1024; off <<= 1) {
    unsigned y = (t >= off) ? s[t - off] : 0u;
    __syncthreads();
    s[t] += y;
    __syncthreads();
  }
  if (t < nb) bsum[t] = s[t] - v;
}

__global__ __launch_bounds__(256) void k_scan3(unsigned* __restrict__ out,
                                               const unsigned* __restrict__ bsum, int M) {
  int i = blockIdx.x * 256 + threadIdx.x;
  if (i < M) out[i] += bsum[blockIdx.x];
}

// ---------- bin edges into bucket-major regions ----------
__global__ __launch_bounds__(256) void k_binwrite(const int* __restrict__ src,
                                                  const int* __restrict__ dst,
                                                  const unsigned* __restrict__ base,
                                                  unsigned* __restrict__ entries,
                                                  int E, int chunk, int NB) {
  __shared__ unsigned cur[128];
  int t = threadIdx.x, blk = blockIdx.x;
  for (int b = t; b < NB; b += 256) cur[b] = base[(size_t)b * NBLK + blk];
  __syncthreads();
  int lo = blk * chunk, hi = min(E, lo + chunk);
  for (int j = lo + t; j < hi; j += 256) {
    int d = dst[j];
    int b = d >> 10;
    unsigned pos = atomicAdd(&cur[b], 1u);
    entries[pos] = ((unsigned)src[j] << 10) | (unsigned)(d & (BN - 1));
  }
}

// ---------- per-bucket: one streaming pass -> deg/dinv/row_start ----------
__global__ __launch_bounds__(1024) void k_degscan(const unsigned* __restrict__ entries,
                                                  const unsigned* __restrict__ base,
                                                  unsigned* __restrict__ row_start,
                                                  unsigned* __restrict__ deg,
                                                  float* __restrict__ dinv,
                                                  int N, int NB, int E) {
  __shared__ unsigned cnt[BN];
  __shared__ unsigned sc[BN];
  int t = threadIdx.x, b = blockIdx.x;
  cnt[t] = 0u;
  __syncthreads();
  unsigned start = base[(size_t)b * NBLK];
  unsigned end = (b + 1 < NB) ? base[(size_t)(b + 1) * NBLK] : (unsigned)E;
  for (unsigned j = start + t; j < end; j += 1024) atomicAdd(&cnt[entries[j] & (BN - 1)], 1u);
  __syncthreads();
  unsigned v = cnt[t];
  sc[t] = v;
  __syncthreads();
#pragma unroll
  for (int off = 1; off < BN; off <<= 1) {
    unsigned y = (t >= off) ? sc[t - off] : 0u;
    __syncthreads();
    sc[t] += y;
    __syncthreads();
  }
  int node = b * BN + t;
  if (node < N) {
    row_start[node] = start + (sc[t] - v);
    deg[node] = v;
    dinv[node] = rsqrtf((float)(v + 1u));
  }
}

// ---------- quarter-bucket CSR: sort in LDS, write esrc sequentially ----------
__global__ __launch_bounds__(512) void k_qcsr(const unsigned* __restrict__ entries,
                                              const unsigned* __restrict__ base,
                                              const unsigned* __restrict__ row_start,
                                              unsigned* __restrict__ esrc,
                                              int N, int NB, int E) {
  int b = blockIdx.x >> 2, q = blockIdx.x & 3;
  int qfirst = b * BN + q * 256;
  if (qfirst >= N) return;
  __shared__ unsigned off[257];
  __shared__ unsigned cur[256];
  __shared__ unsigned srt[QCAP];
  int t = threadIdx.x;
  unsigned start = base[(size_t)b * NBLK];
  unsigned end = (b + 1 < NB) ? base[(size_t)(b + 1) * NBLK] : (unsigned)E;
  if (t < 257) {
    int node = qfirst + t;
    off[t] = (node < N) ? row_start[node] : end;
  }
  __syncthreads();
  unsigned qbase = off[0];
  unsigned count = off[256] - qbase;
  if (count <= QCAP) {
    if (t < 256) cur[t] = off[t] - qbase;
    __syncthreads();
    for (unsigned j = start + t; j < end; j += 512) {
      unsigned en = entries[j];
      unsigned dl = en & (BN - 1);
      if ((int)(dl >> 8) == q) {
        unsigned p = atomicAdd(&cur[dl & 255], 1u);
        srt[p] = en >> 10;
      }
    }
    __syncthreads();
    for (unsigned i = t; i < count; i += 512) esrc[qbase + i] = srt[i];
  } else {                       // fallback (never for uniform data): direct scatter
    if (t < 256) cur[t] = off[t];
    __syncthreads();
    for (unsigned j = start + t; j < end; j += 512) {
      unsigned en = entries[j];
      unsigned dl = en & (BN - 1);
      if ((int)(dl >> 8) == q) esrc[atomicAdd(&cur[dl & 255], 1u)] = en >> 10;
    }
  }
}

// ---------------- hs = fp16( dinv * (x @ W1) ), x:[N,128] W1:[128,16] ----------------
__global__ __launch_bounds__(256) void k_gemm1(const float* __restrict__ x,
                                               const float* __restrict__ W1,
                                               const float* __restrict__ dinv,
                                               __half* __restrict__ hs, int N) {
  __shared__ float xs[16][132];
  __shared__ float wT[16][132];
  int t = threadIdx.x;
#pragma unroll
  for (int i = 0; i < 8; ++i) {
    int idx = t + i * 256;
    int k = idx >> 4, c = idx & 15;
    wT[c][k] = W1[idx];
  }
  int row0 = blockIdx.x * 16;
#pragma unroll
  for (int i = 0; i < 2; ++i) {
    int idx = t + i * 256;
    int r = idx >> 5, c4 = idx & 31;
    float4 v = make_float4(0.f, 0.f, 0.f, 0.f);
    if (row0 + r < N) v = *(const float4*)(x + (size_t)(row0 + r) * N_FIN + c4 * 4);
    *(float4*)&xs[r][c4 * 4] = v;
  }
  __syncthreads();
  int col = t & 15, r = t >> 4;
  float acc = 0.f;
#pragma unroll
  for (int kc = 0; kc < 32; ++kc) {
    float4 xv = *(const float4*)&xs[r][kc * 4];
    float4 wv = *(const float4*)&wT[col][kc * 4];
    acc += xv.x * wv.x + xv.y * wv.y + xv.z * wv.z + xv.w * wv.w;
  }
  int row = row0 + r;
  if (row < N) hs[(size_t)row * N_HID + col] = __float2half(dinv[row] * acc);
}

__device__ __forceinline__ float4 h4f(uint2 v) {
  __half2 h0 = *(__half2*)&v.x, h1 = *(__half2*)&v.y;
  float2 f0 = __half22float2(h0), f1 = __half22float2(h1);
  return make_float4(f0.x, f0.y, f1.x, f1.y);
}
#define ACC(a, v) { float4 f = h4f(v); a.x += f.x; a.y += f.y; a.z += f.z; a.w += f.w; }

// ------ layer1: CSR gather (uint2, 4 lanes/node) + self + bias + relu + 16x12 GEMM ------
__global__ __launch_bounds__(256) void k_gagg1(const unsigned* __restrict__ esrc,
                                               const unsigned* __restrict__ row_start,
                                               const unsigned* __restrict__ deg,
                                               const uint2* __restrict__ hs,
                                               const float* __restrict__ dinv,
                                               const float* __restrict__ b1,
                                               const float* __restrict__ W2,
                                               __half* __restrict__ hs2, int N) {
  __shared__ float os[64][17];
  __shared__ float w2s[N_HID][N_OUT];
  __shared__ float b1s[N_HID];
  int t = threadIdx.x;
  if (t < N_HID * N_OUT) w2s[t / N_OUT][t % N_OUT] = W2[t];
  if (t < N_HID) b1s[t] = b1[t];
  __syncthreads();
  int nl = t >> 2, c4 = t & 3;
  int node = blockIdx.x * 64 + nl;
  if (node < N) {
    unsigned s0 = row_start[node], dn = deg[node];
    float4 a0 = make_float4(0.f, 0.f, 0.f, 0.f), a1 = a0, a2 = a0, a3 = a0;
    unsigned j = 0;
    for (; j + 8 <= dn; j += 8) {
      unsigned e0 = esrc[s0 + j],     e1 = esrc[s0 + j + 1];
      unsigned e2 = esrc[s0 + j + 2], e3 = esrc[s0 + j + 3];
      unsigned e4 = esrc[s0 + j + 4], e5 = esrc[s0 + j + 5];
      unsigned e6 = esrc[s0 + j + 6], e7 = esrc[s0 + j + 7];
      uint2 v0 = hs[(size_t)e0 * 4 + c4], v1 = hs[(size_t)e1 * 4 + c4];
      uint2 v2 = hs[(size_t)e2 * 4 + c4], v3 = hs[(size_t)e3 * 4 + c4];
      uint2 v4 = hs[(size_t)e4 * 4 + c4], v5 = hs[(size_t)e5 * 4 + c4];
      uint2 v6 = hs[(size_t)e6 * 4 + c4], v7 = hs[(size_t)e7 * 4 + c4];
      ACC(a0, v0); ACC(a1, v1); ACC(a2, v2); ACC(a3, v3);
      ACC(a0, v4); ACC(a1, v5); ACC(a2, v6); ACC(a3, v7);
    }
    for (; j < dn; ++j) {
      uint2 v = hs[(size_t)esrc[s0 + j] * 4 + c4];
      ACC(a0, v);
    }
    float4 sf = h4f(hs[(size_t)node * 4 + c4]);
    float di = dinv[node];
    int cb = c4 * 4;
    os[nl][cb + 0] = fmaxf(di * (a0.x + a1.x + a2.x + a3.x + sf.x) + b1s[cb + 0], 0.f);
    os[nl][cb + 1] = fmaxf(di * (a0.y + a1.y + a2.y + a3.y + sf.y) + b1s[cb + 1], 0.f);
    os[nl][cb + 2] = fmaxf(di * (a0.z + a1.z + a2.z + a3.z + sf.z) + b1s[cb + 2], 0.f);
    os[nl][cb + 3] = fmaxf(di * (a0.w + a1.w + a2.w + a3.w + sf.w) + b1s[cb + 3], 0.f);
  }
  __syncthreads();
  for (int idx = t; idx < 64 * 16; idx += 256) {
    int n2 = idx >> 4, cc = idx & 15;
    int node2 = blockIdx.x * 64 + n2;
    if (node2 < N) {
      float s = 0.f;
      if (cc < N_OUT) {
#pragma unroll
        for (int k = 0; k < N_HID; ++k) s += os[n2][k] * w2s[k][cc];
        s *= dinv[node2];
      }
      hs2[(size_t)node2 * N_HID + cc] = __float2half(s);
    }
  }
}

// ------ layer2: CSR gather (uint2, 4 lanes/node) + self + bias + log_softmax ------
__global__ __launch_bounds__(256) void k_gagg2(const unsigned* __restrict__ esrc,
                                               const unsigned* __restrict__ row_start,
                                               const unsigned* __restrict__ deg,
                                               const uint2* __restrict__ hs2,
                                               const float* __restrict__ dinv,
                                               const float* __restrict__ b2,
                                               float* __restrict__ out, int N) {
  __shared__ float zs[64][13];
  __shared__ float ls[64];
  __shared__ float b2s[N_OUT];
  int t = threadIdx.x;
  if (t < N_OUT) b2s[t] = b2[t];
  __syncthreads();
  int nl = t >> 2, c4 = t & 3;
  int node = blockIdx.x * 64 + nl;
  if (node < N) {
    unsigned s0 = row_start[node], dn = deg[node];
    float4 a0 = make_float4(0.f, 0.f, 0.f, 0.f), a1 = a0, a2 = a0, a3 = a0;
    unsigned j = 0;
    for (; j + 8 <= dn; j += 8) {
      unsigned e0 = esrc[s0 + j],     e1 = esrc[s0 + j + 1];
      unsigned e2 = esrc[s0 + j + 2], e3 = esrc[s0 + j + 3];
      unsigned e4 = esrc[s0 + j + 4], e5 = esrc[s0 + j + 5];
      unsigned e6 = esrc[s0 + j + 6], e7 = esrc[s0 + j + 7];
      uint2 v0 = hs2[(size_t)e0 * 4 + c4], v1 = hs2[(size_t)e1 * 4 + c4];
      uint2 v2 = hs2[(size_t)e2 * 4 + c4], v3 = hs2[(size_t)e3 * 4 + c4];
      uint2 v4 = hs2[(size_t)e4 * 4 + c4], v5 = hs2[(size_t)e5 * 4 + c4];
      uint2 v6 = hs2[(size_t)e6 * 4 + c4], v7 = hs2[(size_t)e7 * 4 + c4];
      ACC(a0, v0); ACC(a1, v1); ACC(a2, v2); ACC(a3, v3);
      ACC(a0, v4); ACC(a1, v5); ACC(a2, v6); ACC(a3, v7);
    }
    for (; j < dn; ++j) {
      uint2 v = hs2[(size_t)esrc[s0 + j] * 4 + c4];
      ACC(a0, v);
    }
    if (c4 < 3) {
      float4 sf = h4f(hs2[(size_t)node * 4 + c4]);
      float di = dinv[node];
      int cb = c4 * 4;
      zs[nl][cb + 0] = di * (a0.x + a1.x + a2.x + a3.x + sf.x) + b2s[cb + 0];
      zs[nl][cb + 1] = di * (a0.y + a1.y + a2.y + a3.y + sf.y) + b2s[cb + 1];
      zs[nl][cb + 2] = di * (a0.z + a1.z + a2.z + a3.z + sf.z) + b2s[cb + 2];
      zs[nl][cb + 3] = di * (a0.w + a1.w + a2.w + a3.w + sf.w) + b2s[cb + 3];
    }
  }
  __syncthreads();
  if (t < 64) {
    int node2 = blockIdx.x * 64 + t;
    if (node2 < N) {
      float m = zs[t][0];
#pragma unroll
      for (int jj = 1; jj < N_OUT; ++jj) m = fmaxf(m, zs[t][jj]);
      float sum = 0.f;
#pragma unroll
      for (int jj = 0; jj < N_OUT; ++jj) sum += __expf(zs[t][jj] - m);
      ls[t] = m + __logf(sum);
    }
  }
  __syncthreads();
  for (int idx = t; idx < 64 * N_OUT; idx += 256) {
    int n2 = idx / N_OUT, cc = idx % N_OUT;
    int node2 = blockIdx.x * 64 + n2;
    if (node2 < N) out[(size_t)node2 * N_OUT + cc] = zs[n2][cc] - ls[n2];
  }
}

extern "C" void kernel_launch(void* const* d_in, const int* in_sizes, int n_in,
                              void* d_out, int out_size, void* d_ws, size_t ws_size,
                              hipStream_t stream) {
  const float* x  = (const float*)d_in[0];
  const int*   ei = (const int*)d_in[1];
  const float* W1 = (const float*)d_in[2];
  const float* b1 = (const float*)d_in[3];
  const float* W2 = (const float*)d_in[4];
  const float* b2 = (const float*)d_in[5];
  int N = in_sizes[0] / N_FIN;
  int E = in_sizes[1] / 2;
  const int* src = ei;
  const int* dst = ei + E;

  int NB = (N + BN - 1) / BN;            // 98 buckets of 1024 nodes
  int M  = NB * NBLK;                    // hist/base table size (~100K)
  int chunk = (E + NBLK - 1) / NBLK;     // edges per binning block
  int sb = (M + 255) / 256;              // scan blocks (392 <= 1024)

  // ws: [hist M][base M][bsum 4096B][dinv N][deg N][row_start N]
  //     [big: entries E (later aliased by fp16 hs N*16 + hs2 N*16)][esrc E]
  char* ws = (char*)d_ws;
  unsigned* hist      = (unsigned*)ws;  ws += (size_t)M * 4;
  unsigned* base      = (unsigned*)ws;  ws += (size_t)M * 4;
  unsigned* bsum      = (unsigned*)ws;  ws += 4096;
  float*    dinv      = (float*)ws;     ws += (size_t)N * 4;
  unsigned* deg       = (unsigned*)ws;  ws += (size_t)N * 4;
  unsigned* row_start = (unsigned*)ws;  ws += (size_t)N * 4;
  size_t big_bytes = (size_t)E * 4;
  size_t hs_bytes  = (size_t)N * N_HID * 2 * 2;   // hs + hs2, fp16
  if (hs_bytes > big_bytes) big_bytes = hs_bytes;
  unsigned* entries = (unsigned*)ws;
  __half*   hs      = (__half*)ws;                             // aliases entries (dead after qcsr)
  __half*   hs2     = (__half*)(ws + (size_t)N * N_HID * 2);
  ws += big_bytes;
  unsigned* esrc    = (unsigned*)ws;

  k_hist    <<<NBLK, 256, 0, stream>>>(dst, hist, E, chunk, NB);
  k_scan1   <<<sb, 256, 0, stream>>>(hist, base, bsum, M);
  k_scan2   <<<1, 1024, 0, stream>>>(bsum, sb);
  k_scan3   <<<sb, 256, 0, stream>>>(base, bsum, M);
  k_binwrite<<<NBLK, 256, 0, stream>>>(src, dst, base, entries, E, chunk, NB);
  k_degscan <<<NB, 1024, 0, stream>>>(entries, base, row_start, deg, dinv, N, NB, E);
  k_qcsr    <<<NB * 4, 512, 0, stream>>>(entries, base, row_start, esrc, N, NB, E);
  k_gemm1   <<<(N + 15) / 16, 256, 0, stream>>>(x, W1, dinv, hs, N);   // overwrites entries
  k_gagg1   <<<(N + 63) / 64, 256, 0, stream>>>(esrc, row_start, deg, (const uint2*)hs,
                                                dinv, b1, W2, hs2, N);
  k_gagg2   <<<(N + 63) / 64, 256, 0, stream>>>(esrc, row_start, deg, (const uint2*)hs2,
                                                dinv, b2, (float*)d_out, N);
}

// Round 9
// 135.698 us; speedup vs baseline: 1.4958x; 1.1577x over previous
//
#include <hip/hip_runtime.h>
#include <hip/hip_fp16.h>

#define N_FIN 128
#define N_HID 16
#define N_OUT 12
#define NBLK  1024        // binning blocks (entries layout: block-major, chunk per block)
#define BN    512         // nodes per bucket (dl = dst & 511, bucket = dst >> 9)
#define STCAP 3200        // binsort LDS stage capacity (chunk = 3125)
#define SCAP  17152       // build LDS capacity per bucket (avg 16327, +6.5 sigma)

// ---------- block-local counting sort of a chunk by bucket; coalesced dump ----------
__global__ __launch_bounds__(256) void k_binsort(const int* __restrict__ src,
                                                 const int* __restrict__ dst,
                                                 unsigned* __restrict__ hist,
                                                 unsigned* __restrict__ lstart,
                                                 unsigned* __restrict__ entries,
                                                 int E, int chunk, int NB) {
  __shared__ unsigned lh[256];
  __shared__ unsigned cur[256];
  __shared__ unsigned stage[STCAP];
  int t = threadIdx.x, blk = blockIdx.x;
  for (int b = t; b < NB; b += 256) lh[b] = 0u;
  __syncthreads();
  int clo = blk * chunk, chi = min(E, clo + chunk);
  for (int j = clo + t; j < chi; j += 256) atomicAdd(&lh[dst[j] >> 9], 1u);
  __syncthreads();
  // exclusive scan over buckets (NB <= 256)
  unsigned v = (t < NB) ? lh[t] : 0u;
  cur[t] = v;
  __syncthreads();
#pragma unroll
  for (int off = 1; off < 256; off <<= 1) {
    unsigned y = (t >= off) ? cur[t - off] : 0u;
    __syncthreads();
    cur[t] += y;
    __syncthreads();
  }
  unsigned excl = cur[t] - v;
  if (t < NB) {
    hist[(size_t)t * NBLK + blk]   = v;     // fragment length
    lstart[(size_t)t * NBLK + blk] = excl;  // fragment offset within chunk
  }
  cur[t] = excl;   // own-slot overwrite (no cross-thread read of cur after scan)
  __syncthreads();
  for (int j = clo + t; j < chi; j += 256) {
    int d = dst[j];
    int b = d >> 9;
    unsigned p = atomicAdd(&cur[b], 1u);
    stage[p] = ((unsigned)src[j] << 9) | (unsigned)(d & (BN - 1));
  }
  __syncthreads();
  int n = chi - clo;
  for (int i = t; i < n; i += 256) entries[clo + i] = stage[i];   // coalesced
}

// ---------- exclusive scan of hist (bucket-major) -> base ----------
__global__ __launch_bounds__(256) void k_scan1(const unsigned* __restrict__ in,
                                               unsigned* __restrict__ out,
                                               unsigned* __restrict__ bsum, int M) {
  __shared__ unsigned s[256];
  int t = threadIdx.x, i = blockIdx.x * 256 + t;
  unsigned v = (i < M) ? in[i] : 0u;
  s[t] = v;
  __syncthreads();
#pragma unroll
  for (int off = 1; off < 256; off <<= 1) {
    unsigned y = (t >= off) ? s[t - off] : 0u;
    __syncthreads();
    s[t] += y;
    __syncthreads();
  }
  if (i < M) out[i] = s[t] - v;
  if (t == 255) bsum[blockIdx.x] = s[255];
}

__global__ __launch_bounds__(1024) void k_scan2(unsigned* __restrict__ bsum, int nb) {
  __shared__ unsigned s[1024];
  int t = threadIdx.x;
  unsigned v = (t < nb) ? bsum[t] : 0u;
  s[t] = v;
  __syncthreads();
#pragma unroll
  for (int off = 1; off < 1024; off <<= 1) {
    unsigned y = (t >= off) ? s[t - off] : 0u;
    __syncthreads();
    s[t] += y;
    __syncthreads();
  }
  if (t < nb) bsum[t] = s[t] - v;
}

__global__ __launch_bounds__(256) void k_scan3(unsigned* __restrict__ out,
                                               const unsigned* __restrict__ bsum, int M) {
  int i = blockIdx.x * 256 + threadIdx.x;
  if (i < M) out[i] += bsum[blockIdx.x];
}

// ---------- per-bucket build: coalesced fragment reads -> deg/dinv/row_start + CSR esrc ----------
__device__ __forceinline__ int frag_search(const unsigned* cum, unsigned i) {
  int lo = 0, hi = 1024;
  while (hi - lo > 1) { int mid = (lo + hi) >> 1; if (cum[mid] <= i) lo = mid; else hi = mid; }
  return lo;
}

__global__ __launch_bounds__(1024) void k_build(const unsigned* __restrict__ entries,
                                                const unsigned* __restrict__ base,
                                                const unsigned* __restrict__ lstart,
                                                unsigned* __restrict__ row_start,
                                                unsigned* __restrict__ deg,
                                                float* __restrict__ dinv,
                                                unsigned* __restrict__ esrc,
                                                int N, int NB, int E, int chunk) {
  __shared__ unsigned cum[1025];
  __shared__ unsigned lst[1024];
  __shared__ unsigned cnt[BN];
  __shared__ unsigned cur[BN];
  __shared__ unsigned raw[SCAP];
  __shared__ unsigned srt[SCAP];
  int t = threadIdx.x, b = blockIdx.x;
  unsigned bstart = base[(size_t)b * NBLK];
  unsigned bend = (b + 1 < NB) ? base[(size_t)(b + 1) * NBLK] : (unsigned)E;
  unsigned tot = bend - bstart;
  cum[t] = base[(size_t)b * NBLK + t] - bstart;
  lst[t] = lstart[(size_t)b * NBLK + t];
  if (t == 0) cum[1024] = tot;
  if (t < BN) cnt[t] = 0u;
  __syncthreads();
  bool fits = (tot <= SCAP);
  // pass A: coalesced-read fragments, stage raw, histogram dl
  for (unsigned i = t; i < tot; i += 1024) {
    int f = frag_search(cum, i);
    unsigned en = entries[(size_t)f * chunk + lst[f] + (i - cum[f])];
    if (fits) raw[i] = en;
    atomicAdd(&cnt[en & (BN - 1)], 1u);
  }
  __syncthreads();
  // exclusive scan of cnt[BN]
  unsigned v = (t < BN) ? cnt[t] : 0u;
  if (t < BN) cur[t] = v;
  __syncthreads();
#pragma unroll
  for (int off = 1; off < BN; off <<= 1) {
    unsigned y = (t < BN && t >= off) ? cur[t - off] : 0u;
    __syncthreads();
    if (t < BN) cur[t] += y;
    __syncthreads();
  }
  if (t < BN) {
    unsigned excl = cur[t] - v;
    cur[t] = fits ? excl : (bstart + excl);
    int node = b * BN + t;
    if (node < N) {
      row_start[node] = bstart + excl;
      deg[node] = v;
      dinv[node] = rsqrtf((float)(v + 1u));
    }
  }
  __syncthreads();
  if (fits) {
    // pass B: LDS scatter to CSR order, then coalesced dump
    for (unsigned i = t; i < tot; i += 1024) {
      unsigned en = raw[i];
      unsigned p = atomicAdd(&cur[en & (BN - 1)], 1u);
      srt[p] = en >> 9;
    }
    __syncthreads();
    for (unsigned i = t; i < tot; i += 1024) esrc[bstart + i] = srt[i];
  } else {
    // fallback: direct global scatter (correct, slow; never for uniform data)
    for (unsigned i = t; i < tot; i += 1024) {
      int f = frag_search(cum, i);
      unsigned en = entries[(size_t)f * chunk + lst[f] + (i - cum[f])];
      unsigned p = atomicAdd(&cur[en & (BN - 1)], 1u);
      esrc[p] = en >> 9;
    }
  }
}

// ---------------- hs = fp16( dinv * (x @ W1) ), x:[N,128] W1:[128,16] ----------------
__global__ __launch_bounds__(256) void k_gemm1(const float* __restrict__ x,
                                               const float* __restrict__ W1,
                                               const float* __restrict__ dinv,
                                               __half* __restrict__ hs, int N) {
  __shared__ float xs[16][132];
  __shared__ float wT[16][132];
  int t = threadIdx.x;
#pragma unroll
  for (int i = 0; i < 8; ++i) {
    int idx = t + i * 256;
    int k = idx >> 4, c = idx & 15;
    wT[c][k] = W1[idx];
  }
  int row0 = blockIdx.x * 16;
#pragma unroll
  for (int i = 0; i < 2; ++i) {
    int idx = t + i * 256;
    int r = idx >> 5, c4 = idx & 31;
    float4 v = make_float4(0.f, 0.f, 0.f, 0.f);
    if (row0 + r < N) v = *(const float4*)(x + (size_t)(row0 + r) * N_FIN + c4 * 4);
    *(float4*)&xs[r][c4 * 4] = v;
  }
  __syncthreads();
  int col = t & 15, r = t >> 4;
  float acc = 0.f;
#pragma unroll
  for (int kc = 0; kc < 32; ++kc) {
    float4 xv = *(const float4*)&xs[r][kc * 4];
    float4 wv = *(const float4*)&wT[col][kc * 4];
    acc += xv.x * wv.x + xv.y * wv.y + xv.z * wv.z + xv.w * wv.w;
  }
  int row = row0 + r;
  if (row < N) hs[(size_t)row * N_HID + col] = __float2half(dinv[row] * acc);
}

__device__ __forceinline__ float4 h4f(uint2 v) {
  __half2 h0 = *(__half2*)&v.x, h1 = *(__half2*)&v.y;
  float2 f0 = __half22float2(h0), f1 = __half22float2(h1);
  return make_float4(f0.x, f0.y, f1.x, f1.y);
}
#define ACC(a, v) { float4 f = h4f(v); a.x += f.x; a.y += f.y; a.z += f.z; a.w += f.w; }

// ------ layer1: CSR gather (uint2, 4 lanes/node) + self + bias + relu + 16x12 GEMM ------
__global__ __launch_bounds__(256) void k_gagg1(const unsigned* __restrict__ esrc,
                                               const unsigned* __restrict__ row_start,
                                               const unsigned* __restrict__ deg,
                                               const uint2* __restrict__ hs,
                                               const float* __restrict__ dinv,
                                               const float* __restrict__ b1,
                                               const float* __restrict__ W2,
                                               __half* __restrict__ hs2, int N) {
  __shared__ float os[64][17];
  __shared__ float w2s[N_HID][N_OUT];
  __shared__ float b1s[N_HID];
  int t = threadIdx.x;
  if (t < N_HID * N_OUT) w2s[t / N_OUT][t % N_OUT] = W2[t];
  if (t < N_HID) b1s[t] = b1[t];
  __syncthreads();
  int nl = t >> 2, c4 = t & 3;
  int node = blockIdx.x * 64 + nl;
  if (node < N) {
    unsigned s0 = row_start[node], dn = deg[node];
    float4 a0 = make_float4(0.f, 0.f, 0.f, 0.f), a1 = a0, a2 = a0, a3 = a0;
    unsigned j = 0;
    for (; j + 8 <= dn; j += 8) {
      unsigned e0 = esrc[s0 + j],     e1 = esrc[s0 + j + 1];
      unsigned e2 = esrc[s0 + j + 2], e3 = esrc[s0 + j + 3];
      unsigned e4 = esrc[s0 + j + 4], e5 = esrc[s0 + j + 5];
      unsigned e6 = esrc[s0 + j + 6], e7 = esrc[s0 + j + 7];
      uint2 v0 = hs[(size_t)e0 * 4 + c4], v1 = hs[(size_t)e1 * 4 + c4];
      uint2 v2 = hs[(size_t)e2 * 4 + c4], v3 = hs[(size_t)e3 * 4 + c4];
      uint2 v4 = hs[(size_t)e4 * 4 + c4], v5 = hs[(size_t)e5 * 4 + c4];
      uint2 v6 = hs[(size_t)e6 * 4 + c4], v7 = hs[(size_t)e7 * 4 + c4];
      ACC(a0, v0); ACC(a1, v1); ACC(a2, v2); ACC(a3, v3);
      ACC(a0, v4); ACC(a1, v5); ACC(a2, v6); ACC(a3, v7);
    }
    for (; j < dn; ++j) {
      uint2 v = hs[(size_t)esrc[s0 + j] * 4 + c4];
      ACC(a0, v);
    }
    float4 sf = h4f(hs[(size_t)node * 4 + c4]);
    float di = dinv[node];
    int cb = c4 * 4;
    os[nl][cb + 0] = fmaxf(di * (a0.x + a1.x + a2.x + a3.x + sf.x) + b1s[cb + 0], 0.f);
    os[nl][cb + 1] = fmaxf(di * (a0.y + a1.y + a2.y + a3.y + sf.y) + b1s[cb + 1], 0.f);
    os[nl][cb + 2] = fmaxf(di * (a0.z + a1.z + a2.z + a3.z + sf.z) + b1s[cb + 2], 0.f);
    os[nl][cb + 3] = fmaxf(di * (a0.w + a1.w + a2.w + a3.w + sf.w) + b1s[cb + 3], 0.f);
  }
  __syncthreads();
  for (int idx = t; idx < 64 * 16; idx += 256) {
    int n2 = idx >> 4, cc = idx & 15;
    int node2 = blockIdx.x * 64 + n2;
    if (node2 < N) {
      float s = 0.f;
      if (cc < N_OUT) {
#pragma unroll
        for (int k = 0; k < N_HID; ++k) s += os[n2][k] * w2s[k][cc];
        s *= dinv[node2];
      }
      hs2[(size_t)node2 * N_HID + cc] = __float2half(s);
    }
  }
}

// ------ layer2: CSR gather (uint2, 4 lanes/node) + self + bias + log_softmax ------
__global__ __launch_bounds__(256) void k_gagg2(const unsigned* __restrict__ esrc,
                                               const unsigned* __restrict__ row_start,
                                               const unsigned* __restrict__ deg,
                                               const uint2* __restrict__ hs2,
                                               const float* __restrict__ dinv,
                                               const float* __restrict__ b2,
                                               float* __restrict__ out, int N) {
  __shared__ float zs[64][13];
  __shared__ float ls[64];
  __shared__ float b2s[N_OUT];
  int t = threadIdx.x;
  if (t < N_OUT) b2s[t] = b2[t];
  __syncthreads();
  int nl = t >> 2, c4 = t & 3;
  int node = blockIdx.x * 64 + nl;
  if (node < N) {
    unsigned s0 = row_start[node], dn = deg[node];
    float4 a0 = make_float4(0.f, 0.f, 0.f, 0.f), a1 = a0, a2 = a0, a3 = a0;
    unsigned j = 0;
    for (; j + 8 <= dn; j += 8) {
      unsigned e0 = esrc[s0 + j],     e1 = esrc[s0 + j + 1];
      unsigned e2 = esrc[s0 + j + 2], e3 = esrc[s0 + j + 3];
      unsigned e4 = esrc[s0 + j + 4], e5 = esrc[s0 + j + 5];
      unsigned e6 = esrc[s0 + j + 6], e7 = esrc[s0 + j + 7];
      uint2 v0 = hs2[(size_t)e0 * 4 + c4], v1 = hs2[(size_t)e1 * 4 + c4];
      uint2 v2 = hs2[(size_t)e2 * 4 + c4], v3 = hs2[(size_t)e3 * 4 + c4];
      uint2 v4 = hs2[(size_t)e4 * 4 + c4], v5 = hs2[(size_t)e5 * 4 + c4];
      uint2 v6 = hs2[(size_t)e6 * 4 + c4], v7 = hs2[(size_t)e7 * 4 + c4];
      ACC(a0, v0); ACC(a1, v1); ACC(a2, v2); ACC(a3, v3);
      ACC(a0, v4); ACC(a1, v5); ACC(a2, v6); ACC(a3, v7);
    }
    for (; j < dn; ++j) {
      uint2 v = hs2[(size_t)esrc[s0 + j] * 4 + c4];
      ACC(a0, v);
    }
    if (c4 < 3) {
      float4 sf = h4f(hs2[(size_t)node * 4 + c4]);
      float di = dinv[node];
      int cb = c4 * 4;
      zs[nl][cb + 0] = di * (a0.x + a1.x + a2.x + a3.x + sf.x) + b2s[cb + 0];
      zs[nl][cb + 1] = di * (a0.y + a1.y + a2.y + a3.y + sf.y) + b2s[cb + 1];
      zs[nl][cb + 2] = di * (a0.z + a1.z + a2.z + a3.z + sf.z) + b2s[cb + 2];
      zs[nl][cb + 3] = di * (a0.w + a1.w + a2.w + a3.w + sf.w) + b2s[cb + 3];
    }
  }
  __syncthreads();
  if (t < 64) {
    int node2 = blockIdx.x * 64 + t;
    if (node2 < N) {
      float m = zs[t][0];
#pragma unroll
      for (int jj = 1; jj < N_OUT; ++jj) m = fmaxf(m, zs[t][jj]);
      float sum = 0.f;
#pragma unroll
      for (int jj = 0; jj < N_OUT; ++jj) sum += __expf(zs[t][jj] - m);
      ls[t] = m + __logf(sum);
    }
  }
  __syncthreads();
  for (int idx = t; idx < 64 * N_OUT; idx += 256) {
    int n2 = idx / N_OUT, cc = idx % N_OUT;
    int node2 = blockIdx.x * 64 + n2;
    if (node2 < N) out[(size_t)node2 * N_OUT + cc] = zs[n2][cc] - ls[n2];
  }
}

extern "C" void kernel_launch(void* const* d_in, const int* in_sizes, int n_in,
                              void* d_out, int out_size, void* d_ws, size_t ws_size,
                              hipStream_t stream) {
  const float* x  = (const float*)d_in[0];
  const int*   ei = (const int*)d_in[1];
  const float* W1 = (const float*)d_in[2];
  const float* b1 = (const float*)d_in[3];
  const float* W2 = (const float*)d_in[4];
  const float* b2 = (const float*)d_in[5];
  int N = in_sizes[0] / N_FIN;
  int E = in_sizes[1] / 2;
  const int* src = ei;
  const int* dst = ei + E;

  int NB = (N + BN - 1) / BN;            // 196 buckets of 512 nodes
  int M  = NB * NBLK;                    // fragment tables (~200K)
  int chunk = (E + NBLK - 1) / NBLK;     // 3125 edges per binning block (<= STCAP)
  int sb = (M + 255) / 256;              // scan blocks (784 <= 1024)

  // ws: [hist M][base M][lstart M][bsum 4096B][dinv N][deg N][row_start N]
  //     [big: entries E (later aliased by fp16 hs N*16 + hs2 N*16)][esrc E]
  char* ws = (char*)d_ws;
  unsigned* hist      = (unsigned*)ws;  ws += (size_t)M * 4;
  unsigned* base      = (unsigned*)ws;  ws += (size_t)M * 4;
  unsigned* lstart    = (unsigned*)ws;  ws += (size_t)M * 4;
  unsigned* bsum      = (unsigned*)ws;  ws += 4096;
  float*    dinv      = (float*)ws;     ws += (size_t)N * 4;
  unsigned* deg       = (unsigned*)ws;  ws += (size_t)N * 4;
  unsigned* row_start = (unsigned*)ws;  ws += (size_t)N * 4;
  size_t big_bytes = (size_t)E * 4;
  size_t hs_bytes  = (size_t)N * N_HID * 2 * 2;   // hs + hs2, fp16
  if (hs_bytes > big_bytes) big_bytes = hs_bytes;
  unsigned* entries = (unsigned*)ws;
  __half*   hs      = (__half*)ws;                             // aliases entries (dead after build)
  __half*   hs2     = (__half*)(ws + (size_t)N * N_HID * 2);
  ws += big_bytes;
  unsigned* esrc    = (unsigned*)ws;

  k_binsort<<<NBLK, 256, 0, stream>>>(src, dst, hist, lstart, entries, E, chunk, NB);
  k_scan1  <<<sb, 256, 0, stream>>>(hist, base, bsum, M);
  k_scan2  <<<1, 1024, 0, stream>>>(bsum, sb);
  k_scan3  <<<sb, 256, 0, stream>>>(base, bsum, M);
  k_build  <<<NB, 1024, 0, stream>>>(entries, base, lstart, row_start, deg, dinv, esrc,
                                     N, NB, E, chunk);
  k_gemm1  <<<(N + 15) / 16, 256, 0, stream>>>(x, W1, dinv, hs, N);   // overwrites entries
  k_gagg1  <<<(N + 63) / 64, 256, 0, stream>>>(esrc, row_start, deg, (const uint2*)hs,
                                               dinv, b1, W2, hs2, N);
  k_gagg2  <<<(N + 63) / 64, 256, 0, stream>>>(esrc, row_start, deg, (const uint2*)hs2,
                                               dinv, b2, (float*)d_out, N);
}